// Round 7
// baseline (1309.457 us; speedup 1.0000x reference)
//
#include <hip/hip_runtime.h>
#include <hip/hip_bf16.h>
#include <math.h>

#define SS 128
#define BB 32
#define VV 32000
#define EE 32
#define HH 16
#define KK 32                 // 2*HH = GEMM K
#define NROWS (SS*BB)         // 4096
#define NSL 16                // vocab slices per row-tile
#define VT 125                // 16-wide vocab tiles per slice (16*125*16 = 32000)
#define SREP 12               // k_sumexp probe reps (idempotent)
#define RREP 16               // k_rnn probe reps (idempotent)

typedef __attribute__((ext_vector_type(4))) float f32x4;
typedef __attribute__((ext_vector_type(8))) short bf16x8;
typedef __attribute__((ext_vector_type(4))) short s16x4;

// ------------------------------------------------------------------
// Prep: blocks 0..999 convert W_ho->bf16; blocks 1000..1511 do xproj.
// ------------------------------------------------------------------
__global__ __launch_bounds__(256) void k_prep(
    const float* __restrict__ Who, __hip_bfloat16* __restrict__ who_bf,
    const int* __restrict__ tok, const float* __restrict__ emb,
    const float* __restrict__ Wlr, const float* __restrict__ blr,
    const float* __restrict__ Wrl, const float* __restrict__ brl,
    float* __restrict__ xp) {
  if (blockIdx.x < 1000) {
    int i = blockIdx.x * 256 + threadIdx.x;      // < 256000 = VV*KK/4
    f32x4 v = ((const f32x4*)Who)[i];
    s16x4 o;
    #pragma unroll
    for (int q = 0; q < 4; ++q) {
      __hip_bfloat16 h = __float2bfloat16(v[q]);
      o[q] = *reinterpret_cast<short*>(&h);
    }
    ((s16x4*)who_bf)[i] = o;
  } else {
    int g = (blockIdx.x - 1000) * 256 + threadIdx.x;  // < 131072
    int dir = g >> 16;
    int rem = g & 65535;
    int t = rem >> 9;
    int b = (rem >> 4) & 31;
    int j = rem & 15;
    const float* W  = dir ? Wrl : Wlr;
    const float* bv = dir ? brl : blr;
    int tk = tok[t*BB + b];
    const float* er = emb + tk*EE;
    const float* wr = W + j*(EE+HH);
    float acc = bv[j];
    #pragma unroll
    for (int k = 0; k < EE; ++k) acc += er[k] * wr[k];
    xp[g] = acc;
  }
}

// ------------------------------------------------------------------
// RNN (PROBE: RREP reps, idempotent — same comb_bf values rewritten).
// ------------------------------------------------------------------
__global__ __launch_bounds__(512) void k_rnn_fused(
    const float* __restrict__ xp,
    const float* __restrict__ h0lr, const float* __restrict__ h0rl,
    const float* __restrict__ Wlr, const float* __restrict__ Wrl,
    __hip_bfloat16* __restrict__ comb_bf) {
  int dir = blockIdx.x;
  int tid = threadIdx.x;        // 0..511
  int lane = tid & 63;
  int b = tid >> 4;             // 0..31 (batch)
  int j = tid & 15;             // hidden index
  const float* W  = dir ? Wrl : Wlr;
  const float* h0 = dir ? h0rl : h0lr;
  float wh[HH];
  #pragma unroll
  for (int k = 0; k < HH; ++k) wh[k] = W[j*(EE+HH) + EE + k];
  const float* x = xp + dir * (SS*BB*HH);
  int base = lane & 48;
  for (int rep = 0; rep < RREP; ++rep) {
    float h = h0[b*HH + j];
    asm volatile("" : "+v"(h));     // defeat cross-rep CSE
    if (dir == 0) comb_bf[0*(BB*KK) + b*KK + j] = __float2bfloat16(h);
    else          comb_bf[(SS-1)*(BB*KK) + b*KK + HH + j] = __float2bfloat16(h);
    int xoff  = dir ? ((SS-1)*BB*HH + tid) : tid;
    int xstep = dir ? -(BB*HH) : (BB*HH);
    float xcur = x[xoff];
    for (int t = 1; t < SS; ++t) {
      float xnext = (t < SS-1) ? x[xoff + xstep] : 0.f;
      xoff += xstep;
      float acc = xcur;
      #pragma unroll
      for (int k = 0; k < HH; ++k)
        acc += wh[k] * __shfl(h, base | k);
      float e = __expf(2.f * acc);
      h = 1.f - 2.f / (e + 1.f);          // tanh(acc)
      int ci = dir ? ((SS-1-t)*(BB*KK) + b*KK + HH + j)
                   : (t*(BB*KK) + b*KK + j);
      comb_bf[ci] = __float2bfloat16(h);
      xcur = xnext;
    }
  }
}

// ------------------------------------------------------------------
// Sum-exp (PROBE: SREP reps, idempotent — part rewritten identically).
// ------------------------------------------------------------------
__global__ __launch_bounds__(256) void k_sumexp(
    const __hip_bfloat16* __restrict__ cb, const __hip_bfloat16* __restrict__ wb,
    const float* __restrict__ bho, float* __restrict__ part) {
  int w = blockIdx.x * 4 + (threadIdx.x >> 6);
  int lane = threadIdx.x & 63;
  int rt = w >> 4;              // 0..255
  int sl = w & 15;              // 0..15
  int v0 = sl * (VT*16);
  int g = lane >> 4, c = lane & 15;
  bf16x8 bfr = *(const bf16x8*)(cb + (size_t)(rt*16 + c)*KK + g*8);
  float s = 0.f;
  for (int rep = 0; rep < SREP; ++rep) {
    s = 0.f;
    asm volatile("" : "+v"(s));     // defeat cross-rep CSE
    for (int t = 0; t < VT; ++t) {
      int v = v0 + t*16;
      bf16x8 af = *(const bf16x8*)(wb + (size_t)(v + c)*KK + g*8);
      f32x4 bh = *(const f32x4*)(bho + v + g*4);
      f32x4 d = __builtin_amdgcn_mfma_f32_16x16x32_bf16(af, bfr, bh, 0, 0, 0);
      s += __expf(d[0]) + __expf(d[1]) + __expf(d[2]) + __expf(d[3]);
    }
  }
  s += __shfl_xor(s, 16);
  s += __shfl_xor(s, 32);
  if (lane < 16)
    part[(size_t)(rt*16 + lane)*NSL + sl] = s;
}

// ------------------------------------------------------------------
// Write: direct 64B-segment stores (R4 version, WREP=1).
// ------------------------------------------------------------------
__global__ __launch_bounds__(256) void k_write(
    const __hip_bfloat16* __restrict__ cb, const __hip_bfloat16* __restrict__ wb,
    const float* __restrict__ bho, const float* __restrict__ part,
    float* __restrict__ out) {
  int w = blockIdx.x * 4 + (threadIdx.x >> 6);
  int lane = threadIdx.x & 63;
  int rt = w >> 4;
  int sl = w & 15;
  int v0 = sl * (VT*16);
  int g = lane >> 4, c = lane & 15;
  size_t row = rt*16 + c;
  const f32x4* pp = (const f32x4*)(part + row*NSL);
  f32x4 p0 = pp[0], p1 = pp[1], p2 = pp[2], p3 = pp[3];
  float s = (p0[0]+p0[1]+p0[2]+p0[3]) + (p1[0]+p1[1]+p1[2]+p1[3])
          + (p2[0]+p2[1]+p2[2]+p2[3]) + (p3[0]+p3[1]+p3[2]+p3[3]);
  float Lr = logf(s);
  bf16x8 bfr = *(const bf16x8*)(cb + row*KK + g*8);
  for (int t = 0; t < VT; ++t) {
    int v = v0 + t*16;
    bf16x8 af = *(const bf16x8*)(wb + (size_t)(v + c)*KK + g*8);
    f32x4 bh = *(const f32x4*)(bho + v + g*4);
    f32x4 cin = bh - Lr;
    f32x4 d = __builtin_amdgcn_mfma_f32_16x16x32_bf16(af, bfr, cin, 0, 0, 0);
    *(f32x4*)(out + row*VV + v + g*4) = d;
  }
}

// ------------------------------------------------------------------
extern "C" void kernel_launch(void* const* d_in, const int* in_sizes, int n_in,
                              void* d_out, int out_size, void* d_ws, size_t ws_size,
                              hipStream_t stream) {
  const int*   tok  = (const int*)d_in[0];
  const float* h0lr = (const float*)d_in[1];
  const float* h0rl = (const float*)d_in[2];
  const float* emb  = (const float*)d_in[3];
  const float* Wlr  = (const float*)d_in[4];
  const float* blr  = (const float*)d_in[5];
  const float* Wrl  = (const float*)d_in[6];
  const float* brl  = (const float*)d_in[7];
  const float* Who  = (const float*)d_in[8];
  const float* bho  = (const float*)d_in[9];
  float* out = (float*)d_out;
  float* ws  = (float*)d_ws;

  float* xp   = ws;                                           // 131072 floats
  float* part = ws + 131072;                                  // 4096*16 = 65536 floats
  __hip_bfloat16* comb_bf = (__hip_bfloat16*)(ws + 196608);   // 131072 bf16
  __hip_bfloat16* who_bf  = (__hip_bfloat16*)(ws + 262144);   // 1024000 bf16

  hipLaunchKernelGGL(k_prep, dim3(1512), dim3(256), 0, stream,
                     Who, who_bf, tok, emb, Wlr, blr, Wrl, brl, xp);
  hipLaunchKernelGGL(k_rnn_fused, dim3(2), dim3(512), 0, stream,
                     xp, h0lr, h0rl, Wlr, Wrl, comb_bf);
  hipLaunchKernelGGL(k_sumexp, dim3(1024), dim3(256), 0, stream,
                     comb_bf, who_bf, bho, part);
  hipLaunchKernelGGL(k_write, dim3(1024), dim3(256), 0, stream,
                     comb_bf, who_bf, bho, part, out);
}

// Round 8
// 220.293 us; speedup vs baseline: 5.9442x; 5.9442x over previous
//
#include <hip/hip_runtime.h>
#include <hip/hip_bf16.h>
#include <math.h>

#define SS 128
#define BB 32
#define VV 32000
#define EE 32
#define HH 16
#define KK 32                 // 2*HH = GEMM K
#define NROWS (SS*BB)         // 4096
#define NSL 16                // vocab slices per row-tile
#define VT 125                // 16-wide vocab tiles per slice (16*125*16 = 32000)

typedef __attribute__((ext_vector_type(4))) float f32x4;
typedef __attribute__((ext_vector_type(8))) short bf16x8;
typedef __attribute__((ext_vector_type(4))) short s16x4;

// lane j of each 16-group receives h from lane j^r (ds_swizzle BitMode)
#define SWZ(h, r) __builtin_bit_cast(float, __builtin_amdgcn_ds_swizzle( \
    __builtin_bit_cast(int, (h)), ((r) << 10) | 0x1F))

// ------------------------------------------------------------------
// Prep: blocks 0..999 convert W_ho->bf16; blocks 1000..1511 do xproj.
// ------------------------------------------------------------------
__global__ __launch_bounds__(256) void k_prep(
    const float* __restrict__ Who, __hip_bfloat16* __restrict__ who_bf,
    const int* __restrict__ tok, const float* __restrict__ emb,
    const float* __restrict__ Wlr, const float* __restrict__ blr,
    const float* __restrict__ Wrl, const float* __restrict__ brl,
    float* __restrict__ xp) {
  if (blockIdx.x < 1000) {
    int i = blockIdx.x * 256 + threadIdx.x;      // < 256000 = VV*KK/4
    f32x4 v = ((const f32x4*)Who)[i];
    s16x4 o;
    #pragma unroll
    for (int q = 0; q < 4; ++q) {
      __hip_bfloat16 h = __float2bfloat16(v[q]);
      o[q] = *reinterpret_cast<short*>(&h);
    }
    ((s16x4*)who_bf)[i] = o;
  } else {
    int g = (blockIdx.x - 1000) * 256 + threadIdx.x;  // < 131072
    int dir = g >> 16;
    int rem = g & 65535;
    int t = rem >> 9;
    int b = (rem >> 4) & 31;
    int j = rem & 15;
    const float* W  = dir ? Wrl : Wlr;
    const float* bv = dir ? brl : blr;
    int tk = tok[t*BB + b];
    const float* er = emb + tk*EE;
    const float* wr = W + j*(EE+HH);
    float acc = bv[j];
    #pragma unroll
    for (int k = 0; k < EE; ++k) acc += er[k] * wr[k];
    xp[g] = acc;
  }
}

// ------------------------------------------------------------------
// RNN: butterfly all-gather recurrence. Per step: 15 INDEPENDENT
// ds_swizzle XOR gathers (one lgkm wait), pairwise-tree FMAs with
// pre-permuted weights wr[r] = Wh[j][j^r], then tanh. No barriers,
// no serialized bpermute chain.
// ------------------------------------------------------------------
__global__ __launch_bounds__(512) void k_rnn_fused(
    const float* __restrict__ xp,
    const float* __restrict__ h0lr, const float* __restrict__ h0rl,
    const float* __restrict__ Wlr, const float* __restrict__ Wrl,
    __hip_bfloat16* __restrict__ comb_bf) {
  int dir = blockIdx.x;
  int tid = threadIdx.x;        // 0..511
  int b = tid >> 4;             // 0..31 (batch)
  int j = tid & 15;             // hidden index
  const float* W  = dir ? Wrl : Wlr;
  const float* h0 = dir ? h0rl : h0lr;
  // pre-permuted recurrence weights: wr[r] multiplies h[j^r]
  float wr[HH];
  #pragma unroll
  for (int r = 0; r < HH; ++r) wr[r] = W[j*(EE+HH) + EE + (j ^ r)];
  const float* x = xp + dir * (SS*BB*HH);
  float h = h0[b*HH + j];
  if (dir == 0) comb_bf[0*(BB*KK) + b*KK + j] = __float2bfloat16(h);
  else          comb_bf[(SS-1)*(BB*KK) + b*KK + HH + j] = __float2bfloat16(h);
  int xoff  = dir ? ((SS-1)*BB*HH + tid) : tid;
  int xstep = dir ? -(BB*HH) : (BB*HH);
  float xcur = x[xoff];
  for (int t = 1; t < SS; ++t) {
    float xnext = (t < SS-1) ? x[xoff + xstep] : 0.f;
    xoff += xstep;
    // butterfly gathers (independent; single wait before use)
    float t1 = SWZ(h, 1),  t2 = SWZ(h, 2),  t3 = SWZ(h, 3),  t4 = SWZ(h, 4);
    float t5 = SWZ(h, 5),  t6 = SWZ(h, 6),  t7 = SWZ(h, 7),  t8 = SWZ(h, 8);
    float t9 = SWZ(h, 9),  t10 = SWZ(h, 10), t11 = SWZ(h, 11), t12 = SWZ(h, 12);
    float t13 = SWZ(h, 13), t14 = SWZ(h, 14), t15 = SWZ(h, 15);
    float a0 = fmaf(wr[0], h,  xcur);
    a0 = fmaf(wr[4],  t4,  a0);
    a0 = fmaf(wr[8],  t8,  a0);
    a0 = fmaf(wr[12], t12, a0);
    float a1 = wr[1] * t1;
    a1 = fmaf(wr[5],  t5,  a1);
    a1 = fmaf(wr[9],  t9,  a1);
    a1 = fmaf(wr[13], t13, a1);
    float a2 = wr[2] * t2;
    a2 = fmaf(wr[6],  t6,  a2);
    a2 = fmaf(wr[10], t10, a2);
    a2 = fmaf(wr[14], t14, a2);
    float a3 = wr[3] * t3;
    a3 = fmaf(wr[7],  t7,  a3);
    a3 = fmaf(wr[11], t11, a3);
    a3 = fmaf(wr[15], t15, a3);
    float acc = (a0 + a1) + (a2 + a3);
    float e = __expf(2.f * acc);
    h = 1.f - 2.f / (e + 1.f);          // tanh(acc)
    int ci = dir ? ((SS-1-t)*(BB*KK) + b*KK + HH + j)
                 : (t*(BB*KK) + b*KK + j);
    comb_bf[ci] = __float2bfloat16(h);
    xcur = xnext;
  }
}

// ------------------------------------------------------------------
// Sum-exp: 4096 waves (1024 blocks, exactly 4/CU). wave = (row-tile rt,
// slice sl): 1 MFMA per vocab tile, 125 tiles. part[row][sl] = partial.
// ------------------------------------------------------------------
__global__ __launch_bounds__(256) void k_sumexp(
    const __hip_bfloat16* __restrict__ cb, const __hip_bfloat16* __restrict__ wb,
    const float* __restrict__ bho, float* __restrict__ part) {
  int w = blockIdx.x * 4 + (threadIdx.x >> 6);
  int lane = threadIdx.x & 63;
  int rt = w >> 4;              // 0..255
  int sl = w & 15;              // 0..15
  int v0 = sl * (VT*16);
  int g = lane >> 4, c = lane & 15;
  bf16x8 bfr = *(const bf16x8*)(cb + (size_t)(rt*16 + c)*KK + g*8);
  float s = 0.f;
  for (int t = 0; t < VT; ++t) {
    int v = v0 + t*16;
    bf16x8 af = *(const bf16x8*)(wb + (size_t)(v + c)*KK + g*8);
    f32x4 bh = *(const f32x4*)(bho + v + g*4);
    f32x4 d = __builtin_amdgcn_mfma_f32_16x16x32_bf16(af, bfr, bh, 0, 0, 0);
    s += __expf(d[0]) + __expf(d[1]) + __expf(d[2]) + __expf(d[3]);
  }
  s += __shfl_xor(s, 16);
  s += __shfl_xor(s, 32);
  if (lane < 16)
    part[(size_t)(rt*16 + lane)*NSL + sl] = s;
}

// ------------------------------------------------------------------
// Write: direct 64B-segment stores; L recomputed from partials.
// ------------------------------------------------------------------
__global__ __launch_bounds__(256) void k_write(
    const __hip_bfloat16* __restrict__ cb, const __hip_bfloat16* __restrict__ wb,
    const float* __restrict__ bho, const float* __restrict__ part,
    float* __restrict__ out) {
  int w = blockIdx.x * 4 + (threadIdx.x >> 6);
  int lane = threadIdx.x & 63;
  int rt = w >> 4;
  int sl = w & 15;
  int v0 = sl * (VT*16);
  int g = lane >> 4, c = lane & 15;
  size_t row = rt*16 + c;
  const f32x4* pp = (const f32x4*)(part + row*NSL);
  f32x4 p0 = pp[0], p1 = pp[1], p2 = pp[2], p3 = pp[3];
  float s = (p0[0]+p0[1]+p0[2]+p0[3]) + (p1[0]+p1[1]+p1[2]+p1[3])
          + (p2[0]+p2[1]+p2[2]+p2[3]) + (p3[0]+p3[1]+p3[2]+p3[3]);
  float Lr = logf(s);
  bf16x8 bfr = *(const bf16x8*)(cb + row*KK + g*8);
  for (int t = 0; t < VT; ++t) {
    int v = v0 + t*16;
    bf16x8 af = *(const bf16x8*)(wb + (size_t)(v + c)*KK + g*8);
    f32x4 bh = *(const f32x4*)(bho + v + g*4);
    f32x4 cin = bh - Lr;
    f32x4 d = __builtin_amdgcn_mfma_f32_16x16x32_bf16(af, bfr, cin, 0, 0, 0);
    *(f32x4*)(out + row*VV + v + g*4) = d;
  }
}

// ------------------------------------------------------------------
extern "C" void kernel_launch(void* const* d_in, const int* in_sizes, int n_in,
                              void* d_out, int out_size, void* d_ws, size_t ws_size,
                              hipStream_t stream) {
  const int*   tok  = (const int*)d_in[0];
  const float* h0lr = (const float*)d_in[1];
  const float* h0rl = (const float*)d_in[2];
  const float* emb  = (const float*)d_in[3];
  const float* Wlr  = (const float*)d_in[4];
  const float* blr  = (const float*)d_in[5];
  const float* Wrl  = (const float*)d_in[6];
  const float* brl  = (const float*)d_in[7];
  const float* Who  = (const float*)d_in[8];
  const float* bho  = (const float*)d_in[9];
  float* out = (float*)d_out;
  float* ws  = (float*)d_ws;

  float* xp   = ws;                                           // 131072 floats
  float* part = ws + 131072;                                  // 4096*16 = 65536 floats
  __hip_bfloat16* comb_bf = (__hip_bfloat16*)(ws + 196608);   // 131072 bf16
  __hip_bfloat16* who_bf  = (__hip_bfloat16*)(ws + 262144);   // 1024000 bf16

  hipLaunchKernelGGL(k_prep, dim3(1512), dim3(256), 0, stream,
                     Who, who_bf, tok, emb, Wlr, blr, Wrl, brl, xp);
  hipLaunchKernelGGL(k_rnn_fused, dim3(2), dim3(512), 0, stream,
                     xp, h0lr, h0rl, Wlr, Wrl, comb_bf);
  hipLaunchKernelGGL(k_sumexp, dim3(1024), dim3(256), 0, stream,
                     comb_bf, who_bf, bho, part);
  hipLaunchKernelGGL(k_write, dim3(1024), dim3(256), 0, stream,
                     comb_bf, who_bf, bho, part, out);
}